// Round 1
// baseline (943.417 us; speedup 1.0000x reference)
//
#include <hip/hip_runtime.h>
#include <hip/hip_bf16.h>
#include <math.h>

// Problem constants
#define Bb   16
#define Cc   128
#define Hh   64
#define Wwid 64
#define Nn   4096          // H*W
#define NHh  8
#define HDd  16
#define BHh  128           // B*NH
#define TCc  384           // 3*C
#define OUTc 512
#define KK2  256           // 2*C

// ---------------------------------------------------------------------------
// K1: CPE depthwise 3x3 conv + residual:  s = dwconv3x3(src, cpe_w) + src
// ---------------------------------------------------------------------------
__global__ void cpe_kernel(const float* __restrict__ src,
                           const float* __restrict__ cpe_w,
                           float* __restrict__ s) {
    int idx = blockIdx.x * blockDim.x + threadIdx.x;
    if (idx >= Bb * Cc * Nn) return;
    int n  = idx & (Nn - 1);
    int bc = idx >> 12;
    int c  = bc & (Cc - 1);
    int x = n & 63, y = n >> 6;
    const float* sp = src + (size_t)bc * Nn;
    const float* w  = cpe_w + c * 9;
    float acc = sp[n];  // residual
#pragma unroll
    for (int ky = 0; ky < 3; ky++) {
        int yy = y + ky - 1;
        if (yy < 0 || yy >= Hh) continue;
#pragma unroll
        for (int kx = 0; kx < 3; kx++) {
            int xx = x + kx - 1;
            if (xx < 0 || xx >= Wwid) continue;
            acc += sp[yy * Wwid + xx] * w[ky * 3 + kx];
        }
    }
    s[idx] = acc;
}

// ---------------------------------------------------------------------------
// K2: global average pool over spatial, per (b,c)
// ---------------------------------------------------------------------------
__global__ void pool_kernel(const float* __restrict__ src, float* __restrict__ pool) {
    int bc = blockIdx.x;  // 0..2047
    const float* sp = src + (size_t)bc * Nn;
    float sum = 0.f;
    for (int i = threadIdx.x; i < Nn; i += 256) sum += sp[i];
    __shared__ float red[256];
    red[threadIdx.x] = sum;
    __syncthreads();
    for (int s2 = 128; s2 > 0; s2 >>= 1) {
        if (threadIdx.x < s2) red[threadIdx.x] += red[threadIdx.x + s2];
        __syncthreads();
    }
    if (threadIdx.x == 0) pool[bc] = red[0] * (1.0f / Nn);
}

// ---------------------------------------------------------------------------
// K2b: ECA conv1d (pad 1 within each batch row of C) + sigmoid
// ---------------------------------------------------------------------------
__global__ void ca_kernel(const float* __restrict__ pool,
                          const float* __restrict__ w3,
                          float* __restrict__ ca) {
    int i = blockIdx.x * 256 + threadIdx.x;  // b*C + c, 2048 total
    if (i >= Bb * Cc) return;
    int c = i & (Cc - 1);
    float left  = (c == 0)        ? 0.f : pool[i - 1];
    float mid   = pool[i];
    float right = (c == Cc - 1)   ? 0.f : pool[i + 1];
    float v = w3[0] * left + w3[1] * mid + w3[2] * right;
    ca[i] = 1.f / (1.f + expf(-v));
}

// ---------------------------------------------------------------------------
// K3: QKV 1x1 conv == GEMM  qkv[b,o,n] = sum_c Wq[o,c] * s[b,c,n]
// grid: (N/64, TC/64, B), block 256.  64x64 tile, BK=16, 4x4 microtile.
// ---------------------------------------------------------------------------
__global__ void __launch_bounds__(256) qkv_gemm(const float* __restrict__ Wq,
                                                const float* __restrict__ s,
                                                float* __restrict__ qkv) {
    int b  = blockIdx.z;
    int m0 = blockIdx.y * 64;
    int n0 = blockIdx.x * 64;
    __shared__ float As[16][65];  // As[k][m]
    __shared__ float Bs[16][65];  // Bs[k][n]
    int tx = threadIdx.x & 15, ty = threadIdx.x >> 4;
    float acc[4][4] = {};
    const float* sb = s + (size_t)b * Cc * Nn;
    for (int k0 = 0; k0 < Cc; k0 += 16) {
        {
            int k = threadIdx.x & 15, m = threadIdx.x >> 4;
#pragma unroll
            for (int p = 0; p < 4; p++)
                As[k][m + p * 16] = Wq[(m0 + m + p * 16) * Cc + k0 + k];
        }
        {
            int n = threadIdx.x & 63, k = threadIdx.x >> 6;
#pragma unroll
            for (int p = 0; p < 4; p++)
                Bs[k + p * 4][n] = sb[(size_t)(k0 + k + p * 4) * Nn + n0 + n];
        }
        __syncthreads();
#pragma unroll
        for (int kk = 0; kk < 16; kk++) {
            float a[4], bb[4];
#pragma unroll
            for (int i = 0; i < 4; i++) a[i] = As[kk][ty * 4 + i];
#pragma unroll
            for (int j = 0; j < 4; j++) bb[j] = Bs[kk][tx * 4 + j];
#pragma unroll
            for (int i = 0; i < 4; i++)
#pragma unroll
                for (int j = 0; j < 4; j++) acc[i][j] += a[i] * bb[j];
        }
        __syncthreads();
    }
#pragma unroll
    for (int i = 0; i < 4; i++) {
        float4 v = make_float4(acc[i][0], acc[i][1], acc[i][2], acc[i][3]);
        *(float4*)&qkv[((size_t)b * TCc + m0 + ty * 4 + i) * Nn + n0 + tx * 4] = v;
    }
}

// ---------------------------------------------------------------------------
// K4: in-place softmax over spatial dim for the k channels of qkv
// one block per row (b, c) -> 2048 rows of 4096
// ---------------------------------------------------------------------------
__global__ void softmax_kernel(float* __restrict__ qkv) {
    int row = blockIdx.x;          // b*C + c
    int b = row >> 7, c = row & (Cc - 1);
    float* p = qkv + (size_t)b * TCc * Nn + (size_t)(Cc + c) * Nn;
    int t = threadIdx.x;
    __shared__ float red[256];
    // max
    float m = -1e30f;
    float vals[16];
#pragma unroll
    for (int j = 0; j < 16; j++) {
        vals[j] = p[t + j * 256];
        m = fmaxf(m, vals[j]);
    }
    red[t] = m; __syncthreads();
    for (int s2 = 128; s2 > 0; s2 >>= 1) {
        if (t < s2) red[t] = fmaxf(red[t], red[t + s2]);
        __syncthreads();
    }
    m = red[0]; __syncthreads();
    // exp + sum
    float sum = 0.f;
#pragma unroll
    for (int j = 0; j < 16; j++) {
        vals[j] = expf(vals[j] - m);
        sum += vals[j];
    }
    red[t] = sum; __syncthreads();
    for (int s2 = 128; s2 > 0; s2 >>= 1) {
        if (t < s2) red[t] += red[t + s2];
        __syncthreads();
    }
    float inv = 1.f / red[0];
#pragma unroll
    for (int j = 0; j < 16; j++) p[t + j * 256] = vals[j] * inv;
}

// ---------------------------------------------------------------------------
// K5: content_lambda[bh,i,o] = sum_n kf[bh,i,n] * vf[bh,o,n]
// one block per head; thread = (i,o)
// ---------------------------------------------------------------------------
__global__ void lambda_kernel(const float* __restrict__ qkv, float* __restrict__ lam) {
    int bh = blockIdx.x;           // 0..127
    int b = bh >> 3, h = bh & 7;
    const float* kf = qkv + (size_t)b * TCc * Nn + (size_t)(Cc + h * HDd) * Nn;
    const float* vf = qkv + (size_t)b * TCc * Nn + (size_t)(2 * Cc + h * HDd) * Nn;
    __shared__ __align__(16) float ks[16][128];
    __shared__ __align__(16) float vs[16][132];   // padded stride
    int i = threadIdx.x >> 4, o = threadIdx.x & 15;
    float acc = 0.f;
    for (int n0 = 0; n0 < Nn; n0 += 128) {
        for (int tt = threadIdx.x; tt < 2048; tt += 256) {
            int r = tt >> 7, cc = tt & 127;
            ks[r][cc] = kf[(size_t)r * Nn + n0 + cc];
            vs[r][cc] = vf[(size_t)r * Nn + n0 + cc];
        }
        __syncthreads();
#pragma unroll
        for (int nn = 0; nn < 128; nn += 4) {
            float4 kv = *(const float4*)&ks[i][nn];
            float4 vv = *(const float4*)&vs[o][nn];
            acc += kv.x * vv.x + kv.y * vv.y + kv.z * vv.z + kv.w * vv.w;
        }
        __syncthreads();
    }
    lam[bh * 256 + i * 16 + o] = acc;
}

// ---------------------------------------------------------------------------
// K6a: position_lambda = depthwise 5x5 conv of v with rel_pos[c % 16]
// ---------------------------------------------------------------------------
__global__ void poslam_kernel(const float* __restrict__ qkv,
                              const float* __restrict__ rel,
                              float* __restrict__ pos) {
    int idx = blockIdx.x * blockDim.x + threadIdx.x;
    if (idx >= Bb * Cc * Nn) return;
    int n  = idx & (Nn - 1);
    int bc = idx >> 12;
    int b  = bc >> 7, c = bc & (Cc - 1);
    int x = n & 63, y = n >> 6;
    const float* vp = qkv + (size_t)b * TCc * Nn + (size_t)(2 * Cc + c) * Nn;
    const float* w  = rel + (c & (HDd - 1)) * 25;
    float acc = 0.f;
#pragma unroll
    for (int ky = 0; ky < 5; ky++) {
        int yy = y + ky - 2;
        if (yy < 0 || yy >= Hh) continue;
#pragma unroll
        for (int kx = 0; kx < 5; kx++) {
            int xx = x + kx - 2;
            if (xx < 0 || xx >= Wwid) continue;
            acc += vp[yy * Wwid + xx] * w[ky * 5 + kx];
        }
    }
    pos[idx] = acc;
}

// ---------------------------------------------------------------------------
// K6b: result1[bh,o,n] = 0.25 * sum_i q[bh,i,n]*lam[bh,i,o] + q[bh,o,n]*pos[bh,o,n]
// grid: BH * (N/256), block 256 (one pixel/thread)
// ---------------------------------------------------------------------------
__global__ void combine_kernel(const float* __restrict__ qkv,
                               const float* __restrict__ lam,
                               const float* __restrict__ pos,
                               float* __restrict__ r1) {
    int bh   = blockIdx.x >> 4;
    int tile = blockIdx.x & 15;
    int n = tile * 256 + threadIdx.x;
    int b = bh >> 3, h = bh & 7;
    __shared__ float lam_s[256];
    lam_s[threadIdx.x] = lam[bh * 256 + threadIdx.x];
    __syncthreads();
    const float* qp = qkv + (size_t)b * TCc * Nn + (size_t)(h * HDd) * Nn;
    float qv[16];
#pragma unroll
    for (int i = 0; i < 16; i++) qv[i] = qp[(size_t)i * Nn + n];
    const float* pp = pos + ((size_t)b * Cc + h * HDd) * Nn;
    float* rp       = r1  + ((size_t)b * Cc + h * HDd) * Nn;
#pragma unroll
    for (int o = 0; o < 16; o++) {
        float co = 0.f;
#pragma unroll
        for (int i2 = 0; i2 < 16; i2++) co += qv[i2] * lam_s[i2 * 16 + o];
        co *= 0.25f;  // scaling = HD^-0.5 factored out of qf
        rp[(size_t)o * Nn + n] = co + qv[o] * pp[(size_t)o * Nn + n];
    }
}

// ---------------------------------------------------------------------------
// K7: output GEMM with fused concat + channel-attention scaling:
// out[b,o,n] = sum_{c<128} Wo[o,c]*r1[b,c,n] + sum_c Wo[o,128+c]*src[b,c,n]*ca[b,c]
// grid: (N/64, OUT/64, B), block 256
// ---------------------------------------------------------------------------
__global__ void __launch_bounds__(256) out_gemm(const float* __restrict__ Wo,
                                                const float* __restrict__ r1,
                                                const float* __restrict__ src,
                                                const float* __restrict__ ca,
                                                float* __restrict__ out) {
    int b  = blockIdx.z;
    int m0 = blockIdx.y * 64;
    int n0 = blockIdx.x * 64;
    __shared__ float As[16][65];
    __shared__ float Bs[16][65];
    int tx = threadIdx.x & 15, ty = threadIdx.x >> 4;
    float acc[4][4] = {};
    const float* r1b  = r1  + (size_t)b * Cc * Nn;
    const float* srcb = src + (size_t)b * Cc * Nn;
    const float* cab  = ca + b * Cc;
    for (int k0 = 0; k0 < KK2; k0 += 16) {
        {
            int k = threadIdx.x & 15, m = threadIdx.x >> 4;
#pragma unroll
            for (int p = 0; p < 4; p++)
                As[k][m + p * 16] = Wo[(m0 + m + p * 16) * KK2 + k0 + k];
        }
        {
            int n = threadIdx.x & 63, k = threadIdx.x >> 6;
#pragma unroll
            for (int p = 0; p < 4; p++) {
                int kk = k0 + k + p * 4;
                float v;
                if (kk < Cc) v = r1b[(size_t)kk * Nn + n0 + n];
                else         v = srcb[(size_t)(kk - Cc) * Nn + n0 + n] * cab[kk - Cc];
                Bs[k + p * 4][n] = v;
            }
        }
        __syncthreads();
#pragma unroll
        for (int kk = 0; kk < 16; kk++) {
            float a[4], bb[4];
#pragma unroll
            for (int i = 0; i < 4; i++) a[i] = As[kk][ty * 4 + i];
#pragma unroll
            for (int j = 0; j < 4; j++) bb[j] = Bs[kk][tx * 4 + j];
#pragma unroll
            for (int i = 0; i < 4; i++)
#pragma unroll
                for (int j = 0; j < 4; j++) acc[i][j] += a[i] * bb[j];
        }
        __syncthreads();
    }
#pragma unroll
    for (int i = 0; i < 4; i++) {
        float4 v = make_float4(acc[i][0], acc[i][1], acc[i][2], acc[i][3]);
        *(float4*)&out[((size_t)b * OUTc + m0 + ty * 4 + i) * Nn + n0 + tx * 4] = v;
    }
}

// ---------------------------------------------------------------------------
extern "C" void kernel_launch(void* const* d_in, const int* in_sizes, int n_in,
                              void* d_out, int out_size, void* d_ws, size_t ws_size,
                              hipStream_t stream) {
    const float* src      = (const float*)d_in[0];  // (16,128,64,64)
    const float* cpe_w    = (const float*)d_in[1];  // (128,1,3,3)
    const float* qkv_w    = (const float*)d_in[2];  // (384,128)
    const float* rel_pos  = (const float*)d_in[3];  // (16,5,5)
    const float* conv1d_w = (const float*)d_in[4];  // (3,)
    const float* out_w    = (const float*)d_in[5];  // (512,256)
    float* out = (float*)d_out;

    // workspace layout (floats)
    float* ws   = (float*)d_ws;
    float* s    = ws;                        // 16*128*4096
    float* qkv  = s + (size_t)Bb * Cc * Nn;  // 16*384*4096
    float* lam  = qkv + (size_t)Bb * TCc * Nn;   // 128*256
    float* pos  = lam + (size_t)BHh * HDd * HDd; // 16*128*4096
    float* r1   = pos + (size_t)Bb * Cc * Nn;    // 16*128*4096
    float* pool = r1 + (size_t)Bb * Cc * Nn;     // 2048
    float* ca   = pool + Bb * Cc;                // 2048

    const int total = Bb * Cc * Nn;  // 8,388,608

    // 1. CPE conv + residual
    cpe_kernel<<<(total + 255) / 256, 256, 0, stream>>>(src, cpe_w, s);
    // 2. pool + ECA
    pool_kernel<<<Bb * Cc, 256, 0, stream>>>(src, pool);
    ca_kernel<<<(Bb * Cc + 255) / 256, 256, 0, stream>>>(pool, conv1d_w, ca);
    // 3. QKV GEMM
    {
        dim3 g(Nn / 64, TCc / 64, Bb);
        qkv_gemm<<<g, 256, 0, stream>>>(qkv_w, s, qkv);
    }
    // 4. softmax over spatial (in place on k channels)
    softmax_kernel<<<Bb * Cc, 256, 0, stream>>>(qkv);
    // 5. content lambda
    lambda_kernel<<<BHh, 256, 0, stream>>>(qkv, lam);
    // 6a. position lambda (5x5 dwconv of v)
    poslam_kernel<<<(total + 255) / 256, 256, 0, stream>>>(qkv, rel_pos, pos);
    // 6b. combine -> result1
    combine_kernel<<<BHh * (Nn / 256), 256, 0, stream>>>(qkv, lam, pos, r1);
    // 7. output GEMM (fused concat + ca scaling)
    {
        dim3 g(Nn / 64, OUTc / 64, Bb);
        out_gemm<<<g, 256, 0, stream>>>(out_w, r1, src, ca, out);
    }
}

// Round 3
// 491.603 us; speedup vs baseline: 1.9191x; 1.9191x over previous
//
#include <hip/hip_runtime.h>
#include <hip/hip_bf16.h>
#include <math.h>

// Problem constants
#define Bb   16
#define Cc   128
#define Hh   64
#define Wwid 64
#define Nn   4096          // H*W
#define NHh  8
#define HDd  16
#define BHh  128           // B*NH
#define TCc  384           // 3*C
#define OUTc 512
#define KK2  256           // 2*C

typedef _Float16 f16x8 __attribute__((ext_vector_type(8)));
typedef float    f32x4 __attribute__((ext_vector_type(4)));

__device__ __forceinline__ ushort f2h_bits(float f) {
    _Float16 h = (_Float16)f;
    ushort u;
    __builtin_memcpy(&u, &h, 2);
    return u;
}

// ---------------------------------------------------------------------------
// K0: fp32 -> fp16 weight conversion
// ---------------------------------------------------------------------------
__global__ void cvt_f16(const float* __restrict__ x, ushort* __restrict__ y, int n) {
    int i = blockIdx.x * 256 + threadIdx.x;
    if (i < n) y[i] = f2h_bits(x[i]);
}

// ---------------------------------------------------------------------------
// K1: CPE depthwise 3x3 conv + residual -> s (fp16, natural [b][c][n])
// ---------------------------------------------------------------------------
__global__ void cpe_kernel(const float* __restrict__ src,
                           const float* __restrict__ cpe_w,
                           ushort* __restrict__ s) {
    int idx = blockIdx.x * blockDim.x + threadIdx.x;
    if (idx >= Bb * Cc * Nn) return;
    int n  = idx & (Nn - 1);
    int bc = idx >> 12;
    int c  = bc & (Cc - 1);
    int x = n & 63, y = n >> 6;
    const float* sp = src + (size_t)bc * Nn;
    const float* w  = cpe_w + c * 9;
    float acc = sp[n];  // residual
#pragma unroll
    for (int ky = 0; ky < 3; ky++) {
        int yy = y + ky - 1;
        if (yy < 0 || yy >= Hh) continue;
#pragma unroll
        for (int kx = 0; kx < 3; kx++) {
            int xx = x + kx - 1;
            if (xx < 0 || xx >= Wwid) continue;
            acc += sp[yy * Wwid + xx] * w[ky * 3 + kx];
        }
    }
    s[idx] = f2h_bits(acc);
}

// ---------------------------------------------------------------------------
// K2: global average pool over spatial, per (b,c)
// ---------------------------------------------------------------------------
__global__ void pool_kernel(const float* __restrict__ src, float* __restrict__ pool) {
    int bc = blockIdx.x;  // 0..2047
    const float* sp = src + (size_t)bc * Nn;
    float sum = 0.f;
    for (int i = threadIdx.x; i < Nn; i += 256) sum += sp[i];
    __shared__ float red[256];
    red[threadIdx.x] = sum;
    __syncthreads();
    for (int s2 = 128; s2 > 0; s2 >>= 1) {
        if (threadIdx.x < s2) red[threadIdx.x] += red[threadIdx.x + s2];
        __syncthreads();
    }
    if (threadIdx.x == 0) pool[bc] = red[0] * (1.0f / Nn);
}

// ---------------------------------------------------------------------------
// K2b: ECA conv1d + sigmoid
// ---------------------------------------------------------------------------
__global__ void ca_kernel(const float* __restrict__ pool,
                          const float* __restrict__ w3,
                          float* __restrict__ ca) {
    int i = blockIdx.x * 256 + threadIdx.x;  // b*C + c, 2048 total
    if (i >= Bb * Cc) return;
    int c = i & (Cc - 1);
    float left  = (c == 0)        ? 0.f : pool[i - 1];
    float mid   = pool[i];
    float right = (c == Cc - 1)   ? 0.f : pool[i + 1];
    float v = w3[0] * left + w3[1] * mid + w3[2] * right;
    ca[i] = 1.f / (1.f + expf(-v));
}

// ---------------------------------------------------------------------------
// K3: transpose s [b][c][n] fp16 -> sT [b][n][c] fp16 (64x64 LDS tiles)
// ---------------------------------------------------------------------------
__global__ void transpose_s(const ushort* __restrict__ s, ushort* __restrict__ sT) {
    int bz = blockIdx.z;
    int c0 = blockIdx.y * 64;
    int n0 = blockIdx.x * 64;
    __shared__ ushort t[64][68];
    int nn = threadIdx.x & 63, c4 = threadIdx.x >> 6;
    const ushort* sp = s + ((size_t)bz * Cc + c0) * Nn + n0;
#pragma unroll
    for (int p = 0; p < 16; p++) {
        int cc = p * 4 + c4;
        t[cc][nn] = sp[(size_t)cc * Nn + nn];
    }
    __syncthreads();
    int cw = threadIdx.x & 63, n4 = threadIdx.x >> 6;
    ushort* dp = sT + ((size_t)bz * Nn + n0) * Cc + c0;
#pragma unroll
    for (int p = 0; p < 16; p++) {
        int n = p * 4 + n4;
        dp[(size_t)n * Cc + cw] = t[cw][n];
    }
}

// ---------------------------------------------------------------------------
// K-GEMM (TN, fp16 MFMA): C[b][m][n] = sum_k A[m][k] * Bt[b][n][k]
// 128x128 tile, BK=32, 256 threads (4 waves, each 64x64 via 4x4 16x16x32 MFMA)
// m97 structure: global_load_lds width-16 staging + ds_read_b128 fragments.
// ---------------------------------------------------------------------------
template<int K, int M>
__global__ void __launch_bounds__(256) gemm_tn(const ushort* __restrict__ A,
                                               const ushort* __restrict__ Bt,
                                               float* __restrict__ C) {
    const int bz = blockIdx.z;
    const int m0 = blockIdx.y * 128;
    const int n0 = blockIdx.x * 128;
    __shared__ __align__(16) ushort Al[128 * 32];
    __shared__ __align__(16) ushort Bl[128 * 32];
    const int tid  = threadIdx.x;
    const int wave = tid >> 6, lane = tid & 63;
    const int r = lane & 15, q = lane >> 4;
    const int wr = wave >> 1, wc = wave & 1;

    const ushort* Ag = A + (size_t)m0 * K;
    const ushort* Bg = Bt + ((size_t)bz * Nn + n0) * K;

    f32x4 acc[4][4] = {};

    for (int k0 = 0; k0 < K; k0 += 32) {
        // stage A-tile and B-tile: 512 chunks of 16B each, seg = wave-uniform
#pragma unroll
        for (int p = 0; p < 2; p++) {
            int seg = p * 4 + wave;          // 0..7 (wave-uniform)
            int idx = seg * 64 + lane;       // chunk 0..511
            int row = idx >> 2, ch = idx & 3;
            const ushort* ga = Ag + (size_t)row * K + k0 + ch * 8;
            const ushort* gb = Bg + (size_t)row * K + k0 + ch * 8;
            __builtin_amdgcn_global_load_lds(
                (const __attribute__((address_space(1))) void*)(const void*)ga,
                (__attribute__((address_space(3))) void*)(void*)(Al + seg * 512),
                16, 0, 0);
            __builtin_amdgcn_global_load_lds(
                (const __attribute__((address_space(1))) void*)(const void*)gb,
                (__attribute__((address_space(3))) void*)(void*)(Bl + seg * 512),
                16, 0, 0);
        }
        __syncthreads();

        const ushort* Apt = Al + (size_t)(wr * 64 + r) * 32 + q * 8;
        const ushort* Bpt = Bl + (size_t)(wc * 64 + r) * 32 + q * 8;
        f16x8 af[4], bf[4];
#pragma unroll
        for (int i = 0; i < 4; i++) af[i] = *(const f16x8*)(Apt + i * 16 * 32);
#pragma unroll
        for (int j = 0; j < 4; j++) bf[j] = *(const f16x8*)(Bpt + j * 16 * 32);
#pragma unroll
        for (int i = 0; i < 4; i++)
#pragma unroll
            for (int j = 0; j < 4; j++)
                acc[i][j] = __builtin_amdgcn_mfma_f32_16x16x32_f16(af[i], bf[j], acc[i][j], 0, 0, 0);
        __syncthreads();
    }

    // C/D layout: col = lane&15 (n), row = (lane>>4)*4 + reg (m)
    float* Cp = C + ((size_t)bz * M + m0 + wr * 64) * Nn + n0 + wc * 64;
#pragma unroll
    for (int i = 0; i < 4; i++)
#pragma unroll
        for (int j = 0; j < 4; j++)
#pragma unroll
            for (int e = 0; e < 4; e++)
                Cp[(size_t)(i * 16 + q * 4 + e) * Nn + j * 16 + r] = acc[i][j][e];
}

// ---------------------------------------------------------------------------
// K4: in-place softmax over spatial for k channels of qkv (fp32)
// ---------------------------------------------------------------------------
__global__ void softmax_kernel(float* __restrict__ qkv) {
    int row = blockIdx.x;          // b*C + c
    int b = row >> 7, c = row & (Cc - 1);
    float* p = qkv + (size_t)b * TCc * Nn + (size_t)(Cc + c) * Nn;
    int t = threadIdx.x;
    __shared__ float red[256];
    float m = -1e30f;
    float vals[16];
#pragma unroll
    for (int j = 0; j < 16; j++) {
        vals[j] = p[t + j * 256];
        m = fmaxf(m, vals[j]);
    }
    red[t] = m; __syncthreads();
    for (int s2 = 128; s2 > 0; s2 >>= 1) {
        if (t < s2) red[t] = fmaxf(red[t], red[t + s2]);
        __syncthreads();
    }
    m = red[0]; __syncthreads();
    float sum = 0.f;
#pragma unroll
    for (int j = 0; j < 16; j++) {
        vals[j] = expf(vals[j] - m);
        sum += vals[j];
    }
    red[t] = sum; __syncthreads();
    for (int s2 = 128; s2 > 0; s2 >>= 1) {
        if (t < s2) red[t] += red[t + s2];
        __syncthreads();
    }
    float inv = 1.f / red[0];
#pragma unroll
    for (int j = 0; j < 16; j++) p[t + j * 256] = vals[j] * inv;
}

// ---------------------------------------------------------------------------
// K5: content_lambda[bh,i,o] = sum_n kf[bh,i,n] * vf[bh,o,n]
// ---------------------------------------------------------------------------
__global__ void lambda_kernel(const float* __restrict__ qkv, float* __restrict__ lam) {
    int bh = blockIdx.x;           // 0..127
    int b = bh >> 3, h = bh & 7;
    const float* kf = qkv + (size_t)b * TCc * Nn + (size_t)(Cc + h * HDd) * Nn;
    const float* vf = qkv + (size_t)b * TCc * Nn + (size_t)(2 * Cc + h * HDd) * Nn;
    __shared__ __align__(16) float ks[16][128];
    __shared__ __align__(16) float vs[16][132];
    int i = threadIdx.x >> 4, o = threadIdx.x & 15;
    float acc = 0.f;
    for (int n0 = 0; n0 < Nn; n0 += 128) {
        for (int tt = threadIdx.x; tt < 2048; tt += 256) {
            int r = tt >> 7, cc = tt & 127;
            ks[r][cc] = kf[(size_t)r * Nn + n0 + cc];
            vs[r][cc] = vf[(size_t)r * Nn + n0 + cc];
        }
        __syncthreads();
#pragma unroll
        for (int nn = 0; nn < 128; nn += 4) {
            float4 kv = *(const float4*)&ks[i][nn];
            float4 vv = *(const float4*)&vs[o][nn];
            acc += kv.x * vv.x + kv.y * vv.y + kv.z * vv.z + kv.w * vv.w;
        }
        __syncthreads();
    }
    lam[bh * 256 + i * 16 + o] = acc;
}

// ---------------------------------------------------------------------------
// K6a: position_lambda = depthwise 5x5 conv of v with rel_pos[c % 16]
// ---------------------------------------------------------------------------
__global__ void poslam_kernel(const float* __restrict__ qkv,
                              const float* __restrict__ rel,
                              float* __restrict__ pos) {
    int idx = blockIdx.x * blockDim.x + threadIdx.x;
    if (idx >= Bb * Cc * Nn) return;
    int n  = idx & (Nn - 1);
    int bc = idx >> 12;
    int b  = bc >> 7, c = bc & (Cc - 1);
    int x = n & 63, y = n >> 6;
    const float* vp = qkv + (size_t)b * TCc * Nn + (size_t)(2 * Cc + c) * Nn;
    const float* w  = rel + (c & (HDd - 1)) * 25;
    float acc = 0.f;
#pragma unroll
    for (int ky = 0; ky < 5; ky++) {
        int yy = y + ky - 2;
        if (yy < 0 || yy >= Hh) continue;
#pragma unroll
        for (int kx = 0; kx < 5; kx++) {
            int xx = x + kx - 2;
            if (xx < 0 || xx >= Wwid) continue;
            acc += vp[yy * Wwid + xx] * w[ky * 5 + kx];
        }
    }
    pos[idx] = acc;
}

// ---------------------------------------------------------------------------
// K6b: combine -> catT lower half (fp16, [b][n][c] with c = h*16+o)
// ---------------------------------------------------------------------------
__global__ void combine_kernel(const float* __restrict__ qkv,
                               const float* __restrict__ lam,
                               const float* __restrict__ pos,
                               ushort* __restrict__ catT) {
    int bh   = blockIdx.x >> 4;
    int tile = blockIdx.x & 15;
    int n = tile * 256 + threadIdx.x;
    int b = bh >> 3, h = bh & 7;
    __shared__ float lam_s[256];
    lam_s[threadIdx.x] = lam[bh * 256 + threadIdx.x];
    __syncthreads();
    const float* qp = qkv + (size_t)b * TCc * Nn + (size_t)(h * HDd) * Nn;
    float qv[16];
#pragma unroll
    for (int i = 0; i < 16; i++) qv[i] = qp[(size_t)i * Nn + n];
    const float* pp = pos + ((size_t)b * Cc + h * HDd) * Nn;
    float vals[16];
#pragma unroll
    for (int o = 0; o < 16; o++) {
        float co = 0.f;
#pragma unroll
        for (int i2 = 0; i2 < 16; i2++) co += qv[i2] * lam_s[i2 * 16 + o];
        vals[o] = co * 0.25f + qv[o] * pp[(size_t)o * Nn + n];  // 0.25 = HD^-0.5
    }
    // pack 16 fp16 -> 32B contiguous write
    uint up[8];
#pragma unroll
    for (int o2 = 0; o2 < 8; o2++)
        up[o2] = (uint)f2h_bits(vals[2 * o2]) | ((uint)f2h_bits(vals[2 * o2 + 1]) << 16);
    uint4* dst = (uint4*)(catT + ((size_t)b * Nn + n) * KK2 + h * HDd);
    dst[0] = make_uint4(up[0], up[1], up[2], up[3]);
    dst[1] = make_uint4(up[4], up[5], up[6], up[7]);
}

// ---------------------------------------------------------------------------
// K6c: catT upper half: catT[b][n][128+c] = src[b][c][n] * ca[b][c]  (fp16)
// ---------------------------------------------------------------------------
__global__ void eca_cat(const float* __restrict__ src, const float* __restrict__ ca,
                        ushort* __restrict__ catT) {
    int bz = blockIdx.z, c0 = blockIdx.y * 64, n0 = blockIdx.x * 64;
    __shared__ ushort t[64][68];
    int nn = threadIdx.x & 63, c4 = threadIdx.x >> 6;
    const float* sp  = src + ((size_t)bz * Cc + c0) * Nn + n0;
    const float* cap = ca + bz * Cc + c0;
#pragma unroll
    for (int p = 0; p < 16; p++) {
        int cc = p * 4 + c4;
        t[cc][nn] = f2h_bits(sp[(size_t)cc * Nn + nn] * cap[cc]);
    }
    __syncthreads();
    int cw = threadIdx.x & 63, n4 = threadIdx.x >> 6;
    ushort* dp = catT + ((size_t)bz * Nn + n0) * KK2 + Cc + c0;
#pragma unroll
    for (int p = 0; p < 16; p++) {
        int n = p * 4 + n4;
        dp[(size_t)n * KK2 + cw] = t[cw][n];
    }
}

// ---------------------------------------------------------------------------
extern "C" void kernel_launch(void* const* d_in, const int* in_sizes, int n_in,
                              void* d_out, int out_size, void* d_ws, size_t ws_size,
                              hipStream_t stream) {
    const float* src      = (const float*)d_in[0];  // (16,128,64,64)
    const float* cpe_w    = (const float*)d_in[1];  // (128,1,3,3)
    const float* qkv_w    = (const float*)d_in[2];  // (384,128)
    const float* rel_pos  = (const float*)d_in[3];  // (16,5,5)
    const float* conv1d_w = (const float*)d_in[4];  // (3,)
    const float* out_w    = (const float*)d_in[5];  // (512,256)
    float* out = (float*)d_out;

    // workspace layout
    char* ws = (char*)d_ws;
    float*  qkv   = (float*)ws;                                  ws += (size_t)Bb * TCc * Nn * 4;  // 100.7 MB
    float*  pos   = (float*)ws;                                  ws += (size_t)Bb * Cc * Nn * 4;   // 33.5 MB
    ushort* catT  = (ushort*)ws;                                 ws += (size_t)Bb * Nn * KK2 * 2;  // 33.5 MB
    ushort* sT    = (ushort*)ws;                                 ws += (size_t)Bb * Nn * Cc * 2;   // 16.8 MB
    ushort* s16   = (ushort*)catT;  /* s (dead after transpose) overlays catT */
    float*  lam   = (float*)ws;                                  ws += (size_t)BHh * HDd * HDd * 4;
    float*  pool  = (float*)ws;                                  ws += Bb * Cc * 4;
    float*  ca    = (float*)ws;                                  ws += Bb * Cc * 4;
    ushort* wq16  = (ushort*)ws;                                 ws += (size_t)TCc * Cc * 2;
    ushort* wo16  = (ushort*)ws;                                 ws += (size_t)OUTc * KK2 * 2;

    const int total = Bb * Cc * Nn;  // 8,388,608

    // 0. weight conversion
    cvt_f16<<<(TCc * Cc + 255) / 256, 256, 0, stream>>>(qkv_w, wq16, TCc * Cc);
    cvt_f16<<<(OUTc * KK2 + 255) / 256, 256, 0, stream>>>(out_w, wo16, OUTc * KK2);
    // 1. CPE conv + residual (fp16 out, natural layout; overlays catT region)
    cpe_kernel<<<(total + 255) / 256, 256, 0, stream>>>(src, cpe_w, s16);
    // 2. pool + ECA
    pool_kernel<<<Bb * Cc, 256, 0, stream>>>(src, pool);
    ca_kernel<<<(Bb * Cc + 255) / 256, 256, 0, stream>>>(pool, conv1d_w, ca);
    // 3. transpose s -> sT  (s dead afterwards, catT space reusable)
    {
        dim3 g(Nn / 64, Cc / 64, Bb);
        transpose_s<<<g, 256, 0, stream>>>(s16, sT);
    }
    // 4. QKV GEMM (MFMA fp16): qkv[b][o][n] = Wq[o][:] . sT[b][n][:]
    {
        dim3 g(Nn / 128, TCc / 128, Bb);
        gemm_tn<Cc, TCc><<<g, 256, 0, stream>>>(wq16, sT, qkv);
    }
    // 5. softmax over spatial (in place on k channels)
    softmax_kernel<<<Bb * Cc, 256, 0, stream>>>(qkv);
    // 6. content lambda
    lambda_kernel<<<BHh, 256, 0, stream>>>(qkv, lam);
    // 7. position lambda (5x5 dwconv of v)
    poslam_kernel<<<(total + 255) / 256, 256, 0, stream>>>(qkv, rel_pos, pos);
    // 8. combine -> catT[:, :, 0:128]
    combine_kernel<<<BHh * (Nn / 256), 256, 0, stream>>>(qkv, lam, pos, catT);
    // 9. eca scale + transpose -> catT[:, :, 128:256]
    {
        dim3 g(Nn / 64, Cc / 64, Bb);
        eca_cat<<<g, 256, 0, stream>>>(src, ca, catT);
    }
    // 10. output GEMM (MFMA fp16, fused concat + ca already in catT)
    {
        dim3 g(Nn / 128, OUTc / 128, Bb);
        gemm_tn<KK2, OUTc><<<g, 256, 0, stream>>>(wo16, catT, out);
    }
}